// Round 1
// baseline (189.520 us; speedup 1.0000x reference)
//
#include <hip/hip_runtime.h>
#include <cstdint>

// Problem constants (B=2, C=64, H=W=256, s=16): nH=nW=16, nS=256, N=65536.
// M_COEF=0 => the two grid channels are identically zero everywhere and can be
// dropped from distances, num and den. AFF_SOFTMAX=1 => logits = -d.

#define WDIM   256
#define NPIX   65536     // H*W
#define NSUP   256       // supertokens per batch
#define OUT_F4 8388608u  // 2*256*65536 / 4
#define WS_Z_F4 8320u    // (num 32768 + den 512) / 4

__device__ __forceinline__ unsigned short f2bf(float f) {
    unsigned u = __float_as_uint(f);
    u = (u + 0x7FFFu + ((u >> 16) & 1u)) >> 16;   // round-to-nearest-even
    return (unsigned short)u;
}
__device__ __forceinline__ float bf2f(unsigned short h) {
    return __uint_as_float(((unsigned)h) << 16);
}

// ---------------------------------------------------------------------------
// K0: zero d_out (128 MiB) and the num/den accumulators in ws.
__global__ __launch_bounds__(256) void kfill(float4* __restrict__ out4,
                                             float4* __restrict__ ws4) {
    unsigned idx = blockIdx.x * 256u + threadIdx.x;
    float4 z = make_float4(0.f, 0.f, 0.f, 0.f);
    if (idx < OUT_F4) {
        out4[idx] = z;
    } else {
        unsigned k = idx - OUT_F4;
        if (k < WS_Z_F4) ws4[8192u + k] = z;   // floats [32768, 66048)
    }
}

// ---------------------------------------------------------------------------
// K1: cent0[b][s][c] = mean over 16x16 block. Block = (b, c, sy): reads a
// contiguous 16-row slab (4096 floats) as float4, reduces per supertoken col.
__global__ __launch_bounds__(256) void kcent0(const float* __restrict__ x,
                                              float* __restrict__ cent0) {
    __shared__ float red[64];
    int blk = blockIdx.x;                 // 2*64*16 = 2048 blocks
    int b  = blk >> 10;
    int c  = (blk >> 4) & 63;
    int sy = blk & 15;
    const float4* s4 = (const float4*)(x + (((size_t)b << 22) | ((size_t)c << 16) | ((size_t)sy << 12)));
    int u = threadIdx.x;
    float4 a0 = s4[u], a1 = s4[u + 256], a2 = s4[u + 512], a3 = s4[u + 768];
    float p = (a0.x + a0.y + a0.z + a0.w) + (a1.x + a1.y + a1.z + a1.w)
            + (a2.x + a2.y + a2.z + a2.w) + (a3.x + a3.y + a3.z + a3.w);
    // lane l of each wave owns float4-column l (x-cols 4l..4l+3); sum groups of 4
    p += __shfl_xor(p, 1, 64);
    p += __shfl_xor(p, 2, 64);
    int lane = u & 63, wv = u >> 6;
    if ((lane & 3) == 0) red[wv * 16 + (lane >> 2)] = p;
    __syncthreads();
    if (u < 16) {
        float v = (red[u] + red[16 + u] + red[32 + u] + red[48 + u]) * (1.0f / 256.0f);
        cent0[(((b << 8) | (sy << 4) | u) << 6) + c] = v;
    }
}

// ---------------------------------------------------------------------------
// K2: iteration-0 weights + scatter of num/den. Block = (b, supertoken),
// thread = pixel. Centroid reads are block-uniform (scalar loads).
// Reduction: register-tiled outer product over LDS-staged bf16 pixels.
__global__ __launch_bounds__(256) void kiter0(const float* __restrict__ x,
                                              const float* __restrict__ cent0,
                                              float* __restrict__ num,
                                              float* __restrict__ den) {
    __shared__ __align__(16) float smem[12544];          // 50176 B
    float* w_lds = smem;                                  // [256][12] fp32
    unsigned short* pS = (unsigned short*)(smem + 3072);  // [256][70] bf16
    float* part = smem + 3072;                            // [16][592] (aliases pS after barrier)

    int blk = blockIdx.x;            // b*256 + s
    int b = blk >> 8, sidx = blk & 255;
    int sy = sidx >> 4, sx = sidx & 15;
    int t  = threadIdx.x;
    int py = t >> 4, px = t & 15;
    int n  = ((sy << 4) + py) * WDIM + (sx << 4) + px;
    const float* xp = x + ((size_t)b << 22) + n;
    const float* cb = cent0 + ((size_t)b << 14);

    int candj[9]; bool valj[9];
#pragma unroll
    for (int j = 0; j < 9; j++) {
        int cy = sy + j / 3 - 1, cx = sx + j % 3 - 1;
        bool v = (cy >= 0) && (cy < 16) && (cx >= 0) && (cx < 16);
        valj[j] = v;
        candj[j] = v ? ((cy << 4) | cx) : 0;   // 0 is a safe dummy address
    }

    float d[9];
#pragma unroll
    for (int j = 0; j < 9; j++) d[j] = 0.f;

#pragma unroll 8
    for (int cq = 0; cq < 32; cq++) {          // 2 channels per iter
        float pc0 = xp[(size_t)(2 * cq) << 16];
        float pc1 = xp[(size_t)(2 * cq + 1) << 16];
#pragma unroll
        for (int j = 0; j < 9; j++) {
            float c0 = cb[(candj[j] << 6) + 2 * cq];
            float c1 = cb[(candj[j] << 6) + 2 * cq + 1];
            float f0 = pc0 - c0, f1 = pc1 - c1;
            d[j] = fmaf(f0, f0, d[j]);
            d[j] = fmaf(f1, f1, d[j]);
        }
        *(ushort2*)&pS[t * 70 + 2 * cq] = make_ushort2(f2bf(pc0), f2bf(pc1));
    }

    // softmax over the 9 candidates (invalid -> weight 0)
    float M = -1e30f;
#pragma unroll
    for (int j = 0; j < 9; j++) if (valj[j]) M = fmaxf(M, -d[j]);
    float w[9], Z = 0.f;
#pragma unroll
    for (int j = 0; j < 9; j++) { w[j] = valj[j] ? __expf(-d[j] - M) : 0.f; Z += w[j]; }
    float rZ = 1.0f / Z;
#pragma unroll
    for (int j = 0; j < 9; j++) { w[j] *= rZ; w_lds[t * 12 + j] = w[j]; }

    __syncthreads();

    // Phase B: out[j][c] = sum_t w[t][j]*p[t][c]; thread = (pixel-group tg, channel-quad cg)
    int tg = t >> 4, cg = t & 15;
    float acc[9][4];
    float dacc[9];
#pragma unroll
    for (int j = 0; j < 9; j++) {
        dacc[j] = 0.f;
        acc[j][0] = 0.f; acc[j][1] = 0.f; acc[j][2] = 0.f; acc[j][3] = 0.f;
    }
#pragma unroll 4
    for (int i = 0; i < 16; i++) {
        int tt = (tg << 4) + i;
        float4 wA = *(const float4*)&w_lds[tt * 12];
        float4 wB = *(const float4*)&w_lds[tt * 12 + 4];
        float  w8 = w_lds[tt * 12 + 8];
        ushort2 A2 = *(const ushort2*)&pS[tt * 70 + 4 * cg];
        ushort2 B2 = *(const ushort2*)&pS[tt * 70 + 4 * cg + 2];
        float p0 = bf2f(A2.x), p1 = bf2f(A2.y), p2v = bf2f(B2.x), p3v = bf2f(B2.y);
        float ww[9] = {wA.x, wA.y, wA.z, wA.w, wB.x, wB.y, wB.z, wB.w, w8};
#pragma unroll
        for (int j = 0; j < 9; j++) {
            dacc[j] += ww[j];
            acc[j][0] = fmaf(ww[j], p0, acc[j][0]);
            acc[j][1] = fmaf(ww[j], p1, acc[j][1]);
            acc[j][2] = fmaf(ww[j], p2v, acc[j][2]);
            acc[j][3] = fmaf(ww[j], p3v, acc[j][3]);
        }
    }

    __syncthreads();   // all pS reads done; part may now alias it

#pragma unroll
    for (int j = 0; j < 9; j++)
        *(float4*)&part[tg * 592 + (j << 6) + (cg << 2)] =
            make_float4(acc[j][0], acc[j][1], acc[j][2], acc[j][3]);
    if (cg == 0) {
#pragma unroll
        for (int j = 0; j < 9; j++) part[tg * 592 + 576 + j] = dacc[j];  // den partials
    }

    __syncthreads();

    // Final reduce over the 16 tg-partials + global atomic scatter.
    for (int o = t; o < 585; o += 256) {
        float s = 0.f;
#pragma unroll
        for (int tg2 = 0; tg2 < 16; tg2++) s += part[tg2 * 592 + o];
        if (o < 576) {
            int j = o >> 6, c = o & 63;
            int cy = sy + j / 3 - 1, cx = sx + j % 3 - 1;
            if (cy >= 0 && cy < 16 && cx >= 0 && cx < 16)
                atomicAdd(&num[((size_t)((b << 8) | (cy << 4) | cx) << 6) + c], s);
        } else {
            int j = o - 576;
            int cy = sy + j / 3 - 1, cx = sx + j % 3 - 1;
            if (cy >= 0 && cy < 16 && cx >= 0 && cx < 16)
                atomicAdd(&den[(b << 8) | (cy << 4) | cx], s);
        }
    }
}

// ---------------------------------------------------------------------------
// K3: cent1 = num / (den + 1e-16)
__global__ __launch_bounds__(256) void kdiv(const float* __restrict__ num,
                                            const float* __restrict__ den,
                                            float* __restrict__ cent1) {
    int i = blockIdx.x * 256 + threadIdx.x;   // 32768
    cent1[i] = num[i] / (den[i >> 6] + 1e-16f);
}

// ---------------------------------------------------------------------------
// K4: iteration-1 weights, scattered into the (pre-zeroed) output.
__global__ __launch_bounds__(256) void kiter1(const float* __restrict__ x,
                                              const float* __restrict__ cent1,
                                              float* __restrict__ out) {
    int blk = blockIdx.x;
    int b = blk >> 8, sidx = blk & 255;
    int sy = sidx >> 4, sx = sidx & 15;
    int t  = threadIdx.x;
    int py = t >> 4, px = t & 15;
    int n  = ((sy << 4) + py) * WDIM + (sx << 4) + px;
    const float* xp = x + ((size_t)b << 22) + n;
    const float* cb = cent1 + ((size_t)b << 14);

    int candj[9]; bool valj[9];
#pragma unroll
    for (int j = 0; j < 9; j++) {
        int cy = sy + j / 3 - 1, cx = sx + j % 3 - 1;
        bool v = (cy >= 0) && (cy < 16) && (cx >= 0) && (cx < 16);
        valj[j] = v;
        candj[j] = v ? ((cy << 4) | cx) : 0;
    }

    float d[9];
#pragma unroll
    for (int j = 0; j < 9; j++) d[j] = 0.f;

#pragma unroll 8
    for (int cq = 0; cq < 32; cq++) {
        float pc0 = xp[(size_t)(2 * cq) << 16];
        float pc1 = xp[(size_t)(2 * cq + 1) << 16];
#pragma unroll
        for (int j = 0; j < 9; j++) {
            float c0 = cb[(candj[j] << 6) + 2 * cq];
            float c1 = cb[(candj[j] << 6) + 2 * cq + 1];
            float f0 = pc0 - c0, f1 = pc1 - c1;
            d[j] = fmaf(f0, f0, d[j]);
            d[j] = fmaf(f1, f1, d[j]);
        }
    }

    float M = -1e30f;
#pragma unroll
    for (int j = 0; j < 9; j++) if (valj[j]) M = fmaxf(M, -d[j]);
    float w[9], Z = 0.f;
#pragma unroll
    for (int j = 0; j < 9; j++) { w[j] = valj[j] ? __expf(-d[j] - M) : 0.f; Z += w[j]; }
    float rZ = 1.0f / Z;

    float* ob = out + ((size_t)b << 24) + n;
#pragma unroll
    for (int j = 0; j < 9; j++)
        if (valj[j]) ob[(size_t)candj[j] << 16] = w[j] * rZ;
}

// ---------------------------------------------------------------------------
extern "C" void kernel_launch(void* const* d_in, const int* in_sizes, int n_in,
                              void* d_out, int out_size, void* d_ws, size_t ws_size,
                              hipStream_t stream) {
    (void)in_sizes; (void)n_in; (void)out_size; (void)ws_size;
    const float* x = (const float*)d_in[0];
    float* out = (float*)d_out;
    float* ws  = (float*)d_ws;
    // ws layout (floats): cent0[32768] | num[32768] | den[512] | cent1[32768]
    float* cent0 = ws;
    float* num   = ws + 32768;
    float* den   = ws + 65536;
    float* cent1 = ws + 66048;

    kfill <<<32801, 256, 0, stream>>>((float4*)out, (float4*)ws);
    kcent0<<<2048,  256, 0, stream>>>(x, cent0);
    kiter0<<<512,   256, 0, stream>>>(x, cent0, num, den);
    kdiv  <<<128,   256, 0, stream>>>(num, den, cent1);
    kiter1<<<512,   256, 0, stream>>>(x, cent1, out);
}

// Round 2
// 189.251 us; speedup vs baseline: 1.0014x; 1.0014x over previous
//
#include <hip/hip_runtime.h>
#include <cstdint>

// Problem constants (B=2, C=64, H=W=256, s=16): nH=nW=16, nS=256, N=65536.
// M_COEF=0 => grid channels are identically zero => drop them everywhere.
// AFF_SOFTMAX=1 => logits = -d.
//
// Pipeline:
//   kcent0  : 16x16 block means of x -> cent0 ; also zeros num/den
//   kiter0  : softmax weights vs cent0, reduce num[b][s][c], den[b][s] (atomics)
//   kdiv    : cent1 = num / (den + 1e-16)
//   kweights: softmax weights vs cent1 -> dense W[b][j][n]  (4.7 MB)
//   kexpand : stream 134 MB output; A[b][s][n] = W[b][j(s,n)][n] or 0
// ws layout (floats): cent0[32768] | num[32768] | den[512] | cent1[32768] | W[1179648]

__device__ __forceinline__ unsigned short f2bf(float f) {
    unsigned u = __float_as_uint(f);
    u = (u + 0x7FFFu + ((u >> 16) & 1u)) >> 16;   // round-to-nearest-even
    return (unsigned short)u;
}
__device__ __forceinline__ float bf2f(unsigned short h) {
    return __uint_as_float(((unsigned)h) << 16);
}

// ---------------------------------------------------------------------------
// K1: cent0[b][s][c] = mean over 16x16 block. Block = (b, c, sy). Also zeros
// the num/den accumulator region (33280 floats) using blocks 0..129.
__global__ __launch_bounds__(256) void kcent0(const float* __restrict__ x,
                                              float* __restrict__ cent0,
                                              float* __restrict__ numden) {
    __shared__ float red[64];
    int blk = blockIdx.x;                 // 2*64*16 = 2048 blocks
    int u = threadIdx.x;
    if (blk < 130) numden[blk * 256 + u] = 0.f;   // zero num[32768]+den[512]
    int b  = blk >> 10;
    int c  = (blk >> 4) & 63;
    int sy = blk & 15;
    const float4* s4 = (const float4*)(x + (((size_t)b << 22) | ((size_t)c << 16) | ((size_t)sy << 12)));
    float4 a0 = s4[u], a1 = s4[u + 256], a2 = s4[u + 512], a3 = s4[u + 768];
    float p = (a0.x + a0.y + a0.z + a0.w) + (a1.x + a1.y + a1.z + a1.w)
            + (a2.x + a2.y + a2.z + a2.w) + (a3.x + a3.y + a3.z + a3.w);
    p += __shfl_xor(p, 1, 64);
    p += __shfl_xor(p, 2, 64);
    int lane = u & 63, wv = u >> 6;
    if ((lane & 3) == 0) red[wv * 16 + (lane >> 2)] = p;
    __syncthreads();
    if (u < 16) {
        float v = (red[u] + red[16 + u] + red[32 + u] + red[48 + u]) * (1.0f / 256.0f);
        cent0[(((b << 8) | (sy << 4) | u) << 6) + c] = v;
    }
}

// ---------------------------------------------------------------------------
// K2: iteration-0 weights + num/den reduction. Block = (b, supertoken).
// The 9 candidate centroids (576 floats) are staged in LDS and read as
// same-address broadcasts (conflict-free).
__global__ __launch_bounds__(256) void kiter0(const float* __restrict__ x,
                                              const float* __restrict__ cent0,
                                              float* __restrict__ num,
                                              float* __restrict__ den) {
    __shared__ __align__(16) float smem[12608];           // 50432 B
    float* kc    = smem;                                   // [9][64]
    float* w_lds = smem + 576;                             // [256][12]
    unsigned short* pS = (unsigned short*)(smem + 3648);   // [256][70] bf16
    float* part  = smem + 576;                             // [16][592] aliases w_lds/pS post-barrier

    int blk = blockIdx.x;            // b*256 + s
    int b = blk >> 8, sidx = blk & 255;
    int sy = sidx >> 4, sx = sidx & 15;
    int t  = threadIdx.x;
    int py = t >> 4, px = t & 15;
    int n  = ((sy << 4) + py) * 256 + (sx << 4) + px;
    const float* xp = x + ((size_t)b << 22) + n;
    const float* cb = cent0 + ((size_t)b << 14);

    int candj[9]; bool valj[9];
#pragma unroll
    for (int j = 0; j < 9; j++) {
        int cy = sy + j / 3 - 1, cx = sx + j % 3 - 1;
        bool v = (cy >= 0) && (cy < 16) && (cx >= 0) && (cx < 16);
        valj[j] = v;
        candj[j] = v ? ((cy << 4) | cx) : 0;   // 0 = safe dummy row
    }

    // Stage the 9 candidate centroids into LDS (2304 B).
    for (int idx = t; idx < 576; idx += 256) {
        int j = idx >> 6, c = idx & 63;
        kc[idx] = cb[(candj[j] << 6) + c];
    }
    __syncthreads();

    // Distances: channel-quad outer, candidates inner; global p loads are
    // independent per quad so the scheduler can hoist them.
    float d[9];
#pragma unroll
    for (int j = 0; j < 9; j++) d[j] = 0.f;
#pragma unroll
    for (int c = 0; c < 64; c += 4) {
        float p0 = xp[(size_t)(c + 0) << 16];
        float p1 = xp[(size_t)(c + 1) << 16];
        float p2 = xp[(size_t)(c + 2) << 16];
        float p3 = xp[(size_t)(c + 3) << 16];
#pragma unroll
        for (int j = 0; j < 9; j++) {
            float4 k4 = *(const float4*)&kc[(j << 6) + c];
            float f0 = p0 - k4.x, f1 = p1 - k4.y, f2 = p2 - k4.z, f3 = p3 - k4.w;
            d[j] = fmaf(f0, f0, d[j]);
            d[j] = fmaf(f1, f1, d[j]);
            d[j] = fmaf(f2, f2, d[j]);
            d[j] = fmaf(f3, f3, d[j]);
        }
        *(ushort2*)&pS[t * 70 + c]     = make_ushort2(f2bf(p0), f2bf(p1));
        *(ushort2*)&pS[t * 70 + c + 2] = make_ushort2(f2bf(p2), f2bf(p3));
    }

    // softmax over the 9 candidates (invalid -> weight 0)
    float M = -1e30f;
#pragma unroll
    for (int j = 0; j < 9; j++) if (valj[j]) M = fmaxf(M, -d[j]);
    float w[9], Z = 0.f;
#pragma unroll
    for (int j = 0; j < 9; j++) { w[j] = valj[j] ? __expf(-d[j] - M) : 0.f; Z += w[j]; }
    float rZ = 1.0f / Z;
#pragma unroll
    for (int j = 0; j < 9; j++) { w[j] *= rZ; w_lds[t * 12 + j] = w[j]; }

    __syncthreads();

    // Phase B: out[j][c] = sum_t w[t][j]*p[t][c]; thread = (pixel-group, channel-quad)
    int tg = t >> 4, cg = t & 15;
    float acc[9][4];
    float dacc[9];
#pragma unroll
    for (int j = 0; j < 9; j++) {
        dacc[j] = 0.f;
        acc[j][0] = 0.f; acc[j][1] = 0.f; acc[j][2] = 0.f; acc[j][3] = 0.f;
    }
#pragma unroll 4
    for (int i = 0; i < 16; i++) {
        int tt = (tg << 4) + i;
        float4 wA = *(const float4*)&w_lds[tt * 12];
        float4 wB = *(const float4*)&w_lds[tt * 12 + 4];
        float  w8 = w_lds[tt * 12 + 8];
        ushort2 A2 = *(const ushort2*)&pS[tt * 70 + 4 * cg];
        ushort2 B2 = *(const ushort2*)&pS[tt * 70 + 4 * cg + 2];
        float p0 = bf2f(A2.x), p1 = bf2f(A2.y), p2v = bf2f(B2.x), p3v = bf2f(B2.y);
        float ww[9] = {wA.x, wA.y, wA.z, wA.w, wB.x, wB.y, wB.z, wB.w, w8};
#pragma unroll
        for (int j = 0; j < 9; j++) {
            dacc[j] += ww[j];
            acc[j][0] = fmaf(ww[j], p0, acc[j][0]);
            acc[j][1] = fmaf(ww[j], p1, acc[j][1]);
            acc[j][2] = fmaf(ww[j], p2v, acc[j][2]);
            acc[j][3] = fmaf(ww[j], p3v, acc[j][3]);
        }
    }

    __syncthreads();   // all w_lds/pS reads done; part may alias them now

#pragma unroll
    for (int j = 0; j < 9; j++)
        *(float4*)&part[tg * 592 + (j << 6) + (cg << 2)] =
            make_float4(acc[j][0], acc[j][1], acc[j][2], acc[j][3]);
    if (cg == 0) {
#pragma unroll
        for (int j = 0; j < 9; j++) part[tg * 592 + 576 + j] = dacc[j];  // den partials
    }

    __syncthreads();

    // Final reduce over 16 partials + global atomic scatter (<=9-way contention).
    for (int o = t; o < 585; o += 256) {
        float s = 0.f;
#pragma unroll
        for (int tg2 = 0; tg2 < 16; tg2++) s += part[tg2 * 592 + o];
        if (o < 576) {
            int j = o >> 6, c = o & 63;
            int cy = sy + j / 3 - 1, cx = sx + j % 3 - 1;
            if (cy >= 0 && cy < 16 && cx >= 0 && cx < 16)
                atomicAdd(&num[((size_t)((b << 8) | (cy << 4) | cx) << 6) + c], s);
        } else {
            int j = o - 576;
            int cy = sy + j / 3 - 1, cx = sx + j % 3 - 1;
            if (cy >= 0 && cy < 16 && cx >= 0 && cx < 16)
                atomicAdd(&den[(b << 8) | (cy << 4) | cx], s);
        }
    }
}

// ---------------------------------------------------------------------------
// K3: cent1 = num / (den + 1e-16)
__global__ __launch_bounds__(256) void kdiv(const float* __restrict__ num,
                                            const float* __restrict__ den,
                                            float* __restrict__ cent1) {
    int i = blockIdx.x * 256 + threadIdx.x;   // 32768
    cent1[i] = num[i] / (den[i >> 6] + 1e-16f);
}

// ---------------------------------------------------------------------------
// K4: iteration-1 weights -> dense W[b][j][n] (coalesced stores, 4.7 MB).
__global__ __launch_bounds__(256) void kweights(const float* __restrict__ x,
                                                const float* __restrict__ cent1,
                                                float* __restrict__ W) {
    __shared__ __align__(16) float kc[576];
    int blk = blockIdx.x;
    int b = blk >> 8, sidx = blk & 255;
    int sy = sidx >> 4, sx = sidx & 15;
    int t  = threadIdx.x;
    int py = t >> 4, px = t & 15;
    int n  = ((sy << 4) + py) * 256 + (sx << 4) + px;
    const float* xp = x + ((size_t)b << 22) + n;
    const float* cb = cent1 + ((size_t)b << 14);

    int candj[9]; bool valj[9];
#pragma unroll
    for (int j = 0; j < 9; j++) {
        int cy = sy + j / 3 - 1, cx = sx + j % 3 - 1;
        bool v = (cy >= 0) && (cy < 16) && (cx >= 0) && (cx < 16);
        valj[j] = v;
        candj[j] = v ? ((cy << 4) | cx) : 0;
    }

    for (int idx = t; idx < 576; idx += 256) {
        int j = idx >> 6, c = idx & 63;
        kc[idx] = cb[(candj[j] << 6) + c];
    }
    __syncthreads();

    float d[9];
#pragma unroll
    for (int j = 0; j < 9; j++) d[j] = 0.f;
#pragma unroll
    for (int c = 0; c < 64; c += 4) {
        float p0 = xp[(size_t)(c + 0) << 16];
        float p1 = xp[(size_t)(c + 1) << 16];
        float p2 = xp[(size_t)(c + 2) << 16];
        float p3 = xp[(size_t)(c + 3) << 16];
#pragma unroll
        for (int j = 0; j < 9; j++) {
            float4 k4 = *(const float4*)&kc[(j << 6) + c];
            float f0 = p0 - k4.x, f1 = p1 - k4.y, f2 = p2 - k4.z, f3 = p3 - k4.w;
            d[j] = fmaf(f0, f0, d[j]);
            d[j] = fmaf(f1, f1, d[j]);
            d[j] = fmaf(f2, f2, d[j]);
            d[j] = fmaf(f3, f3, d[j]);
        }
    }

    float M = -1e30f;
#pragma unroll
    for (int j = 0; j < 9; j++) if (valj[j]) M = fmaxf(M, -d[j]);
    float w[9], Z = 0.f;
#pragma unroll
    for (int j = 0; j < 9; j++) { w[j] = valj[j] ? __expf(-d[j] - M) : 0.f; Z += w[j]; }
    float rZ = 1.0f / Z;

    float* wb = W + (((size_t)b * 9) << 16) + n;
#pragma unroll
    for (int j = 0; j < 9; j++)
        if (valj[j]) wb[(size_t)j << 16] = w[j] * rZ;
}

// ---------------------------------------------------------------------------
// K5: stream the 134 MB output once. out[b][s][n] = W[b][j][n] if supertoken s
// is candidate j of pixel n, else 0. Pure float4 streaming writes.
__global__ __launch_bounds__(256) void kexpand(const float4* __restrict__ W4,
                                               float4* __restrict__ out4) {
    unsigned g0 = blockIdx.x * 256u + threadIdx.x;
#pragma unroll
    for (int it = 0; it < 4; it++) {
        unsigned g = g0 + (unsigned)it * 2097152u;    // [0, 8388608)
        unsigned b = g >> 22;
        unsigned s = (g >> 14) & 255u;
        unsigned q = g & 16383u;          // float4 index within row (n0 = 4q)
        int syn = (int)(q >> 10);          // (4q>>8)>>4
        int sxn = (int)((q >> 2) & 15u);   // ((4q&255)>>4)
        int dy = (int)(s >> 4)  - syn;
        int dx = (int)(s & 15u) - sxn;
        float4 v = make_float4(0.f, 0.f, 0.f, 0.f);
        if (dy >= -1 && dy <= 1 && dx >= -1 && dx <= 1) {
            int j = (dy + 1) * 3 + (dx + 1);
            v = W4[(((size_t)b * 9 + j) << 14) + q];
        }
        out4[g] = v;
    }
}

// ---------------------------------------------------------------------------
extern "C" void kernel_launch(void* const* d_in, const int* in_sizes, int n_in,
                              void* d_out, int out_size, void* d_ws, size_t ws_size,
                              hipStream_t stream) {
    (void)in_sizes; (void)n_in; (void)out_size; (void)ws_size;
    const float* x = (const float*)d_in[0];
    float* out = (float*)d_out;
    float* ws  = (float*)d_ws;
    float* cent0 = ws;
    float* num   = ws + 32768;
    float* den   = ws + 65536;
    float* cent1 = ws + 66048;
    float* W     = ws + 98816;

    kcent0  <<<2048, 256, 0, stream>>>(x, cent0, num);
    kiter0  <<<512,  256, 0, stream>>>(x, cent0, num, den);
    kdiv    <<<128,  256, 0, stream>>>(num, den, cent1);
    kweights<<<512,  256, 0, stream>>>(x, cent1, W);
    kexpand <<<8192, 256, 0, stream>>>((const float4*)W, (float4*)out);
}

// Round 3
// 187.389 us; speedup vs baseline: 1.0114x; 1.0099x over previous
//
#include <hip/hip_runtime.h>
#include <cstdint>

// Problem constants (B=2, C=64, H=W=256, s=16): nH=nW=16, nS=256, N=65536.
// M_COEF=0 => grid channels are identically zero => dropped everywhere.
// AFF_SOFTMAX=1 => logits = -d. Softmax shift-invariance:
//   softmax_j(-|p-c_j|^2) = softmax_j(2 p.c_j - |c_j|^2)   (|p|^2 cancels)
//
// Pipeline:
//   kcent0  : 16x16 block means of x -> cent0 ; also zeros num/den
//   kiter0  : dot-form softmax weights vs cent0 -> num[b][s][c], den[b][s]
//   kweights: cent1 = num/(den+eps) fused; dot-form weights -> dense W[b][j][n]
//   kexpand : stream 134 MB output; A[b][s][n] = W[b][j(s,n)][n] or 0
// ws layout (floats): cent0[32768] | num[32768] | den[512] | (unused) | W[1179648]

__device__ __forceinline__ unsigned short f2bf(float f) {
    unsigned u = __float_as_uint(f);
    u = (u + 0x7FFFu + ((u >> 16) & 1u)) >> 16;   // round-to-nearest-even
    return (unsigned short)u;
}
__device__ __forceinline__ float bf2f(unsigned short h) {
    return __uint_as_float(((unsigned)h) << 16);
}

// ---------------------------------------------------------------------------
// K1: cent0[b][s][c] = mean over 16x16 block. Block = (b, c, sy). Also zeros
// the num/den accumulator region (33280 floats) using blocks 0..129.
__global__ __launch_bounds__(256) void kcent0(const float* __restrict__ x,
                                              float* __restrict__ cent0,
                                              float* __restrict__ numden) {
    __shared__ float red[64];
    int blk = blockIdx.x;                 // 2*64*16 = 2048 blocks
    int u = threadIdx.x;
    if (blk < 130) numden[blk * 256 + u] = 0.f;   // zero num[32768]+den[512]
    int b  = blk >> 10;
    int c  = (blk >> 4) & 63;
    int sy = blk & 15;
    const float4* s4 = (const float4*)(x + (((size_t)b << 22) | ((size_t)c << 16) | ((size_t)sy << 12)));
    float4 a0 = s4[u], a1 = s4[u + 256], a2 = s4[u + 512], a3 = s4[u + 768];
    float p = (a0.x + a0.y + a0.z + a0.w) + (a1.x + a1.y + a1.z + a1.w)
            + (a2.x + a2.y + a2.z + a2.w) + (a3.x + a3.y + a3.z + a3.w);
    p += __shfl_xor(p, 1, 64);
    p += __shfl_xor(p, 2, 64);
    int lane = u & 63, wv = u >> 6;
    if ((lane & 3) == 0) red[wv * 16 + (lane >> 2)] = p;
    __syncthreads();
    if (u < 16) {
        float v = (red[u] + red[16 + u] + red[32 + u] + red[48 + u]) * (1.0f / 256.0f);
        cent0[(((b << 8) | (sy << 4) | u) << 6) + c] = v;
    }
}

// ---------------------------------------------------------------------------
// K2: iteration-0 weights + num/den reduction. Block = (b, supertoken).
// LDS: kc[9][64] = 2*centroid, cnormS[9] = |c_j|^2; dot-form logits.
__global__ __launch_bounds__(256) void kiter0(const float* __restrict__ x,
                                              const float* __restrict__ cent0,
                                              float* __restrict__ num,
                                              float* __restrict__ den) {
    __shared__ __align__(16) float smem[12624];           // 50496 B
    float* kc     = smem;                                  // [9][64] (2*c)
    float* cnormS = smem + 576;                            // [9] (+pad)
    float* w_lds  = smem + 592;                            // [256][12]
    unsigned short* pS = (unsigned short*)(smem + 3664);   // [256][70] bf16
    float* part   = smem + 592;                            // [16][592] aliases post-barrier

    int blk = blockIdx.x;            // b*256 + s
    int b = blk >> 8, sidx = blk & 255;
    int sy = sidx >> 4, sx = sidx & 15;
    int t  = threadIdx.x;
    int py = t >> 4, px = t & 15;
    int n  = ((sy << 4) + py) * 256 + (sx << 4) + px;
    const float* xp = x + ((size_t)b << 22) + n;
    const float* cb = cent0 + ((size_t)b << 14);

    int candj[9]; bool valj[9];
#pragma unroll
    for (int j = 0; j < 9; j++) {
        int cy = sy + j / 3 - 1, cx = sx + j % 3 - 1;
        bool v = (cy >= 0) && (cy < 16) && (cx >= 0) && (cx < 16);
        valj[j] = v;
        candj[j] = v ? ((cy << 4) | cx) : 0;   // 0 = safe dummy row
    }

    // Stage 2*centroid into LDS; 9 threads compute |c_j|^2 from global.
    for (int idx = t; idx < 576; idx += 256) {
        int j = idx >> 6, c = idx & 63;
        kc[idx] = 2.0f * cb[(candj[j] << 6) + c];
    }
    if (t < 9) {
        const float* cr = cb + (candj[t] << 6);
        float cn = 0.f;
        for (int c = 0; c < 64; c++) { float v = cr[c]; cn = fmaf(v, v, cn); }
        cnormS[t] = cn;
    }
    __syncthreads();

    // dot_j = 2 p . c_j  (1 fma per (channel, candidate))
    float d[9];
#pragma unroll
    for (int j = 0; j < 9; j++) d[j] = 0.f;
#pragma unroll
    for (int c = 0; c < 64; c += 4) {
        float p0 = xp[(size_t)(c + 0) << 16];
        float p1 = xp[(size_t)(c + 1) << 16];
        float p2 = xp[(size_t)(c + 2) << 16];
        float p3 = xp[(size_t)(c + 3) << 16];
#pragma unroll
        for (int j = 0; j < 9; j++) {
            float4 k4 = *(const float4*)&kc[(j << 6) + c];
            d[j] = fmaf(p0, k4.x, d[j]);
            d[j] = fmaf(p1, k4.y, d[j]);
            d[j] = fmaf(p2, k4.z, d[j]);
            d[j] = fmaf(p3, k4.w, d[j]);
        }
        *(ushort2*)&pS[t * 70 + c]     = make_ushort2(f2bf(p0), f2bf(p1));
        *(ushort2*)&pS[t * 70 + c + 2] = make_ushort2(f2bf(p2), f2bf(p3));
    }

    // softmax over logits l_j = dot_j - |c_j|^2 (invalid -> weight 0)
    float l[9];
    float M = -1e30f;
#pragma unroll
    for (int j = 0; j < 9; j++) {
        l[j] = d[j] - cnormS[j];
        if (valj[j]) M = fmaxf(M, l[j]);
    }
    float w[9], Z = 0.f;
#pragma unroll
    for (int j = 0; j < 9; j++) { w[j] = valj[j] ? __expf(l[j] - M) : 0.f; Z += w[j]; }
    float rZ = 1.0f / Z;
#pragma unroll
    for (int j = 0; j < 9; j++) { w[j] *= rZ; w_lds[t * 12 + j] = w[j]; }

    __syncthreads();

    // Phase B: num[j][c] = sum_t w[t][j]*p[t][c]; thread = (pixel-group, channel-quad)
    int tg = t >> 4, cg = t & 15;
    float acc[9][4];
    float dacc[9];
#pragma unroll
    for (int j = 0; j < 9; j++) {
        dacc[j] = 0.f;
        acc[j][0] = 0.f; acc[j][1] = 0.f; acc[j][2] = 0.f; acc[j][3] = 0.f;
    }
#pragma unroll 4
    for (int i = 0; i < 16; i++) {
        int tt = (tg << 4) + i;
        float4 wA = *(const float4*)&w_lds[tt * 12];
        float4 wB = *(const float4*)&w_lds[tt * 12 + 4];
        float  w8 = w_lds[tt * 12 + 8];
        ushort2 A2 = *(const ushort2*)&pS[tt * 70 + 4 * cg];
        ushort2 B2 = *(const ushort2*)&pS[tt * 70 + 4 * cg + 2];
        float p0 = bf2f(A2.x), p1 = bf2f(A2.y), p2v = bf2f(B2.x), p3v = bf2f(B2.y);
        float ww[9] = {wA.x, wA.y, wA.z, wA.w, wB.x, wB.y, wB.z, wB.w, w8};
#pragma unroll
        for (int j = 0; j < 9; j++) {
            dacc[j] += ww[j];
            acc[j][0] = fmaf(ww[j], p0, acc[j][0]);
            acc[j][1] = fmaf(ww[j], p1, acc[j][1]);
            acc[j][2] = fmaf(ww[j], p2v, acc[j][2]);
            acc[j][3] = fmaf(ww[j], p3v, acc[j][3]);
        }
    }

    __syncthreads();   // all w_lds/pS reads done; part may alias them now

#pragma unroll
    for (int j = 0; j < 9; j++)
        *(float4*)&part[tg * 592 + (j << 6) + (cg << 2)] =
            make_float4(acc[j][0], acc[j][1], acc[j][2], acc[j][3]);
    if (cg == 0) {
#pragma unroll
        for (int j = 0; j < 9; j++) part[tg * 592 + 576 + j] = dacc[j];  // den partials
    }

    __syncthreads();

    // Final reduce over 16 partials + global atomic scatter (<=9-way contention).
    for (int o = t; o < 585; o += 256) {
        float s = 0.f;
#pragma unroll
        for (int tg2 = 0; tg2 < 16; tg2++) s += part[tg2 * 592 + o];
        if (o < 576) {
            int j = o >> 6, c = o & 63;
            int cy = sy + j / 3 - 1, cx = sx + j % 3 - 1;
            if (cy >= 0 && cy < 16 && cx >= 0 && cx < 16)
                atomicAdd(&num[((size_t)((b << 8) | (cy << 4) | cx) << 6) + c], s);
        } else {
            int j = o - 576;
            int cy = sy + j / 3 - 1, cx = sx + j % 3 - 1;
            if (cy >= 0 && cy < 16 && cx >= 0 && cx < 16)
                atomicAdd(&den[(b << 8) | (cy << 4) | cx], s);
        }
    }
}

// ---------------------------------------------------------------------------
// K3: iteration-1 weights -> dense W[b][j][n]. cent1 = num/(den+eps) fused
// into the LDS staging (kdiv kernel eliminated).
__global__ __launch_bounds__(256) void kweights(const float* __restrict__ x,
                                                const float* __restrict__ num,
                                                const float* __restrict__ den,
                                                float* __restrict__ W) {
    __shared__ __align__(16) float smem[608];
    float* kc     = smem;          // [9][64] = 2*cent1
    float* cnormS = smem + 576;    // [9]
    float* rdS    = smem + 592;    // [9]

    int blk = blockIdx.x;
    int b = blk >> 8, sidx = blk & 255;
    int sy = sidx >> 4, sx = sidx & 15;
    int t  = threadIdx.x;
    int py = t >> 4, px = t & 15;
    int n  = ((sy << 4) + py) * 256 + (sx << 4) + px;
    const float* xp = x + ((size_t)b << 22) + n;
    const float* nb = num + ((size_t)b << 14);
    const float* db = den + ((size_t)b << 8);

    int candj[9]; bool valj[9];
#pragma unroll
    for (int j = 0; j < 9; j++) {
        int cy = sy + j / 3 - 1, cx = sx + j % 3 - 1;
        bool v = (cy >= 0) && (cy < 16) && (cx >= 0) && (cx < 16);
        valj[j] = v;
        candj[j] = v ? ((cy << 4) | cx) : 0;
    }

    if (t < 9) rdS[t] = 1.0f / (db[candj[t]] + 1e-16f);
    __syncthreads();
    for (int idx = t; idx < 576; idx += 256) {
        int j = idx >> 6, c = idx & 63;
        kc[idx] = 2.0f * nb[(candj[j] << 6) + c] * rdS[j];
    }
    if (t < 9) {
        const float* nr = nb + (candj[t] << 6);
        float rd = rdS[t], cn = 0.f;
        for (int c = 0; c < 64; c++) { float v = nr[c] * rd; cn = fmaf(v, v, cn); }
        cnormS[t] = cn;
    }
    __syncthreads();

    float d[9];
#pragma unroll
    for (int j = 0; j < 9; j++) d[j] = 0.f;
#pragma unroll
    for (int c = 0; c < 64; c += 4) {
        float p0 = xp[(size_t)(c + 0) << 16];
        float p1 = xp[(size_t)(c + 1) << 16];
        float p2 = xp[(size_t)(c + 2) << 16];
        float p3 = xp[(size_t)(c + 3) << 16];
#pragma unroll
        for (int j = 0; j < 9; j++) {
            float4 k4 = *(const float4*)&kc[(j << 6) + c];
            d[j] = fmaf(p0, k4.x, d[j]);
            d[j] = fmaf(p1, k4.y, d[j]);
            d[j] = fmaf(p2, k4.z, d[j]);
            d[j] = fmaf(p3, k4.w, d[j]);
        }
    }

    float l[9];
    float M = -1e30f;
#pragma unroll
    for (int j = 0; j < 9; j++) {
        l[j] = d[j] - cnormS[j];
        if (valj[j]) M = fmaxf(M, l[j]);
    }
    float w[9], Z = 0.f;
#pragma unroll
    for (int j = 0; j < 9; j++) { w[j] = valj[j] ? __expf(l[j] - M) : 0.f; Z += w[j]; }
    float rZ = 1.0f / Z;

    float* wb = W + (((size_t)b * 9) << 16) + n;
#pragma unroll
    for (int j = 0; j < 9; j++)
        if (valj[j]) wb[(size_t)j << 16] = w[j] * rZ;
}

// ---------------------------------------------------------------------------
// K4: stream the 134 MB output once. out[b][s][n] = W[b][j][n] if supertoken s
// is candidate j of pixel n, else 0. Pure float4 streaming writes.
__global__ __launch_bounds__(256) void kexpand(const float4* __restrict__ W4,
                                               float4* __restrict__ out4) {
    unsigned g0 = blockIdx.x * 256u + threadIdx.x;
#pragma unroll
    for (int it = 0; it < 4; it++) {
        unsigned g = g0 + (unsigned)it * 2097152u;    // [0, 8388608)
        unsigned b = g >> 22;
        unsigned s = (g >> 14) & 255u;
        unsigned q = g & 16383u;          // float4 index within row (n0 = 4q)
        int syn = (int)(q >> 10);
        int sxn = (int)((q >> 2) & 15u);
        int dy = (int)(s >> 4)  - syn;
        int dx = (int)(s & 15u) - sxn;
        float4 v = make_float4(0.f, 0.f, 0.f, 0.f);
        if (dy >= -1 && dy <= 1 && dx >= -1 && dx <= 1) {
            int j = (dy + 1) * 3 + (dx + 1);
            v = W4[(((size_t)b * 9 + j) << 14) + q];
        }
        out4[g] = v;
    }
}

// ---------------------------------------------------------------------------
extern "C" void kernel_launch(void* const* d_in, const int* in_sizes, int n_in,
                              void* d_out, int out_size, void* d_ws, size_t ws_size,
                              hipStream_t stream) {
    (void)in_sizes; (void)n_in; (void)out_size; (void)ws_size;
    const float* x = (const float*)d_in[0];
    float* out = (float*)d_out;
    float* ws  = (float*)d_ws;
    float* cent0 = ws;
    float* num   = ws + 32768;
    float* den   = ws + 65536;
    float* W     = ws + 98816;

    kcent0  <<<2048, 256, 0, stream>>>(x, cent0, num);
    kiter0  <<<512,  256, 0, stream>>>(x, cent0, num, den);
    kweights<<<512,  256, 0, stream>>>(x, num, den, W);
    kexpand <<<8192, 256, 0, stream>>>((const float4*)W, (float4*)out);
}